// Round 8
// baseline (293.756 us; speedup 1.0000x reference)
//
#include <hip/hip_runtime.h>
#include <hip/hip_bf16.h>
#include <math.h>

typedef __bf16 bf16x8 __attribute__((ext_vector_type(8)));
typedef float f32x4 __attribute__((ext_vector_type(4)));
typedef unsigned short u16x4 __attribute__((ext_vector_type(4)));

#define AS1P const __attribute__((address_space(1))) void*
#define AS3P __attribute__((address_space(3))) void*

__device__ __forceinline__ float b2f(unsigned short h) {
    unsigned int u = ((unsigned int)h) << 16;
    return __builtin_bit_cast(float, u);
}
__device__ __forceinline__ unsigned short f2b(float f) {
    unsigned int u = __builtin_bit_cast(unsigned int, f);
    u += 0x7FFFu + ((u >> 16) & 1u);
    return (unsigned short)(u >> 16);
}
__device__ __forceinline__ float silu(float c) {
    return c * __builtin_amdgcn_rcpf(1.0f + __expf(-c));
}

// ---------------- tiled transpose + bf16 convert
__global__ __launch_bounds__(256) void k_convT(const float* __restrict__ src,
                                               unsigned short* __restrict__ dst,
                                               int R, int C) {
    __shared__ float tile[32][33];
    int tx = threadIdx.x, ty = threadIdx.y;
    int r0 = blockIdx.y << 5, c0 = blockIdx.x << 5;
#pragma unroll
    for (int i = 0; i < 4; ++i)
        tile[ty + 8 * i][tx] = src[(long long)(r0 + ty + 8 * i) * C + c0 + tx];
    __syncthreads();
#pragma unroll
    for (int i = 0; i < 4; ++i)
        dst[(long long)(c0 + ty + 8 * i) * R + r0 + tx] = f2b(tile[tx][ty + 8 * i]);
}

// ---------------- LayerNorm
__global__ __launch_bounds__(256) void k_ln(const float* __restrict__ x,
                                            const float* __restrict__ g,
                                            const float* __restrict__ b,
                                            unsigned short* __restrict__ xn) {
    int row = blockIdx.x;
    int t = threadIdx.x;
    const float* xr = x + (long long)row * 768;
    float v0 = xr[t], v1 = xr[t + 256], v2 = xr[t + 512];
    float s = v0 + v1 + v2;
    float q = v0 * v0 + v1 * v1 + v2 * v2;
#pragma unroll
    for (int off = 32; off > 0; off >>= 1) {
        s += __shfl_xor(s, off);
        q += __shfl_xor(q, off);
    }
    __shared__ float ss[4], sq[4];
    int w = t >> 6;
    if ((t & 63) == 0) { ss[w] = s; sq[w] = q; }
    __syncthreads();
    float S_ = ss[0] + ss[1] + ss[2] + ss[3];
    float Q_ = sq[0] + sq[1] + sq[2] + sq[3];
    float mu = S_ * (1.0f / 768.0f);
    float var = Q_ * (1.0f / 768.0f) - mu * mu;
    float rs = rsqrtf(var + 1e-5f);
    unsigned short* xo = xn + (long long)row * 768;
    xo[t]       = f2b((v0 - mu) * rs * g[t]       + b[t]);
    xo[t + 256] = f2b((v1 - mu) * rs * g[t + 256] + b[t + 256]);
    xo[t + 512] = f2b((v2 - mu) * rs * g[t + 512] + b[t + 512]);
}

// ---------------- RoPE + per-head affine
__global__ __launch_bounds__(128) void k_rope(const unsigned short* __restrict__ bS,
                                              const float* __restrict__ gqk,
                                              const float* __restrict__ bqk,
                                              unsigned short* __restrict__ q,
                                              unsigned short* __restrict__ k) {
    int row = blockIdx.x;
    int l = row & 511;
    int s = threadIdx.x;
    int j = s & 63;
    int partner = s ^ 64;
    float b0 = b2f(bS[(long long)row * 128 + s]);
    float bp = b2f(bS[(long long)row * 128 + partner]);
    float invf = __expf((float)j * -0.14391156831f);
    float th = (float)l * invf;
    float sn, cs;
    __sincosf(th, &sn, &cs);
    float sign = (s < 64) ? -1.0f : 1.0f;
    float preq  = b0 * gqk[s]           + bqk[s];
    float preqp = bp * gqk[partner]     + bqk[partner];
    q[(long long)row * 128 + s] = f2b(preq * cs + sign * preqp * sn);
    float prek  = b0 * gqk[128 + s]       + bqk[128 + s];
    float prekp = bp * gqk[128 + partner] + bqk[128 + partner];
    k[(long long)row * 128 + s] = f2b(prek * cs + sign * prekp * sn);
}

// ================= 128^2 2-phase kernel (QK only: P = relu^2(qk/L + bias))
__global__ __launch_bounds__(256) void k_qk(const unsigned short* __restrict__ A,
                                            const unsigned short* __restrict__ B,
                                            const float* __restrict__ wrel,
                                            unsigned short* __restrict__ P) {
    __shared__ __align__(16) unsigned short As[128 * 64];
    __shared__ __align__(16) unsigned short Bs[128 * 64];
    int t = threadIdx.x;
    int w = t >> 6, lane = t & 63;
    int wr = w >> 1, wc = w & 1;
    int bx = blockIdx.x, by = blockIdx.y, bz = blockIdx.z;
    const unsigned short* Ab = A + (long long)bz * 512 * 128 + (long long)by * 128 * 128;
    const unsigned short* Bb = B + (long long)bz * 512 * 128 + (long long)bx * 128 * 128;

    f32x4 acc[4][4];
#pragma unroll
    for (int m = 0; m < 4; ++m)
#pragma unroll
        for (int n = 0; n < 4; ++n) acc[m][n] = (f32x4){0.f, 0.f, 0.f, 0.f};

    int rowA = (w << 3) + (lane >> 3);
    int colA = (lane & 7) << 3;

    for (int k0 = 0; k0 < 128; k0 += 64) {
#pragma unroll
        for (int i = 0; i < 4; ++i) {
            int r = (i << 5) + rowA;
            __builtin_amdgcn_global_load_lds(
                (AS1P)(Ab + (long long)r * 128 + k0 + colA),
                (AS3P)(&As[(i << 11) + (w << 9)]), 16, 0, 0);
            __builtin_amdgcn_global_load_lds(
                (AS1P)(Bb + (long long)r * 128 + k0 + colA),
                (AS3P)(&Bs[(i << 11) + (w << 9)]), 16, 0, 0);
        }
        __syncthreads();
#pragma unroll
        for (int ks = 0; ks < 2; ++ks) {
            bf16x8 af[4], bfr[4];
#pragma unroll
            for (int m = 0; m < 4; ++m)
                af[m] = *(const bf16x8*)&As[((wr << 6) + (m << 4) + (lane & 15)) * 64 +
                                            (ks << 5) + ((lane >> 4) << 3)];
#pragma unroll
            for (int n = 0; n < 4; ++n)
                bfr[n] = *(const bf16x8*)&Bs[((wc << 6) + (n << 4) + (lane & 15)) * 64 +
                                             (ks << 5) + ((lane >> 4) << 3)];
#pragma unroll
            for (int m = 0; m < 4; ++m)
#pragma unroll
                for (int n = 0; n < 4; ++n)
                    acc[m][n] = __builtin_amdgcn_mfma_f32_16x16x32_bf16(bfr[n], af[m],
                                                                        acc[m][n], 0, 0, 0);
        }
        __syncthreads();
    }

    int c15 = lane & 15, qq = lane >> 4;
    int rowb = (by << 7) + (wr << 6) + c15;
    int colb = (bx << 7) + (wc << 6) + (qq << 2);
#pragma unroll
    for (int m = 0; m < 4; ++m) {
#pragma unroll
        for (int n = 0; n < 4; ++n) {
            int grow = rowb + (m << 4);
            int gcol = colb + (n << 4);
            f32x4 a = acc[m][n];
            int base = gcol - grow + 511;
            u16x4 o;
#pragma unroll
            for (int i = 0; i < 4; ++i) {
                float val = a[i] * (1.0f / 512.0f) + wrel[base + i];
                val = fmaxf(val, 0.0f);
                o[i] = f2b(val * val);
            }
            *(u16x4*)(P + ((long long)(bz * 512 + grow)) * 512 + gcol) = o;
        }
    }
}

// ================= 256x256 register-pipelined kernel: BK=64, 2 LDS bufs (128KB),
// 1 barrier + 1 vmcnt per K-tile, counted lgkmcnt sub-phases (frag reg ping-pong).
// LDS rows = 128B, XOR swizzle byte ^= (row&7)<<4 (R3-verified conflict-free).
__device__ __forceinline__ bf16x8 ldsb(const char* p) {
    bf16x8 r;
    unsigned int off =
        (unsigned int)(unsigned long long)(__attribute__((address_space(3))) const void*)p;
    asm volatile("ds_read_b128 %0, %1" : "=v"(r) : "v"(off));
    return r;
}
// stage 64 rows x 128B of a [256][64] bf16 tile; linear LDS dest, swizzled global src
__device__ __forceinline__ void stage64(const unsigned short* __restrict__ g, int ldk,
                                        char* lds, int r0, int w, int lane) {
    int row = r0 + (w << 3) + (lane >> 3);
    int colb = (lane & 7) << 4;
    int scolb = colb ^ ((row & 7) << 4);
    __builtin_amdgcn_global_load_lds(
        (AS1P)((const char*)g + (long long)row * (ldk * 2) + scolb),
        (AS3P)(lds + (r0 << 7) + (w << 10)), 16, 0, 0);
}

template <bool SWAP, int NT>
__device__ __forceinline__ void kloopP(const unsigned short* __restrict__ Ab,
                                       const unsigned short* __restrict__ Bb,
                                       char* A0, char* A1, char* B0, char* B1,
                                       f32x4 (&acc)[8][4], int tid, int wr, int wc,
                                       int o0, int o1) {
    constexpr int K = NT * 64;
    int w = tid >> 6, lane = tid & 63;
    const int abase = wr * 16384;  // wr*128 rows * 128B
    const int bbase = wc * 8192;   // wc*64 rows * 128B
    bf16x8 afA[2], afB[2], bfrA[4], bfrB[4];

#define STAGE(gA, gB, bufA, bufB)                          \
    stage64(gA, K, bufA, 0, w, lane);                      \
    stage64(gA, K, bufA, 64, w, lane);                     \
    stage64(gA, K, bufA, 128, w, lane);                    \
    stage64(gA, K, bufA, 192, w, lane);                    \
    stage64(gB, K, bufB, 0, w, lane);                      \
    stage64(gB, K, bufB, 64, w, lane);                     \
    stage64(gB, K, bufB, 128, w, lane);                    \
    stage64(gB, K, bufB, 192, w, lane);
#define LA(DST, mp, OKS, BUF)                              \
    DST[0] = ldsb((BUF) + abase + (mp) * 4096 + (OKS));    \
    DST[1] = ldsb((BUF) + abase + (mp) * 4096 + 2048 + (OKS));
#define LB(DST, OKS, BUF)                                  \
    DST[0] = ldsb((BUF) + bbase + (OKS));                  \
    DST[1] = ldsb((BUF) + bbase + 2048 + (OKS));           \
    DST[2] = ldsb((BUF) + bbase + 4096 + (OKS));           \
    DST[3] = ldsb((BUF) + bbase + 6144 + (OKS));
#define WAITL(N)                                           \
    asm volatile("s_waitcnt lgkmcnt(" #N ")" ::: "memory");\
    __builtin_amdgcn_sched_barrier(0);
#define MM(mp, BFR, AF)                                                               \
    __builtin_amdgcn_s_setprio(1);                                                    \
    _Pragma("unroll") for (int j_ = 0; j_ < 2; ++j_)                                  \
        _Pragma("unroll") for (int n_ = 0; n_ < 4; ++n_) {                            \
            if constexpr (SWAP)                                                       \
                acc[(mp) * 2 + j_][n_] = __builtin_amdgcn_mfma_f32_16x16x32_bf16(     \
                    BFR[n_], AF[j_], acc[(mp) * 2 + j_][n_], 0, 0, 0);                \
            else                                                                      \
                acc[(mp) * 2 + j_][n_] = __builtin_amdgcn_mfma_f32_16x16x32_bf16(     \
                    AF[j_], BFR[n_], acc[(mp) * 2 + j_][n_], 0, 0, 0);                \
        }                                                                             \
    __builtin_amdgcn_s_setprio(0);
    // sub-phase wait ledger (in-order LDS returns):
    //   entry queue = 6 (bfrA4 + afA2)
    //   s0 +2 w2 | s1 +2 w2 | s2 +6 w6 | s3 +2 w6 | s4 +2 w2 | s5 +2 w2 | s6 +2 w2 | s7 w0
#define TILE(CA, CB, NA, NB, t)                                                       \
    LA(afB, 1, o0, CA) WAITL(2) MM(0, bfrA, afA)                                      \
    LA(afA, 2, o0, CA) WAITL(2) MM(1, bfrA, afB)                                      \
    LA(afB, 3, o0, CA) LB(bfrB, o1, CB) WAITL(6) MM(2, bfrA, afA)                     \
    LA(afA, 0, o1, CA) WAITL(6) MM(3, bfrA, afB)                                      \
    LA(afB, 1, o1, CA) WAITL(2) MM(0, bfrB, afA)                                      \
    LA(afA, 2, o1, CA) WAITL(2) MM(1, bfrB, afB)                                      \
    LA(afB, 3, o1, CA) WAITL(2) MM(2, bfrB, afA)                                      \
    WAITL(0) MM(3, bfrB, afB)                                                         \
    __builtin_amdgcn_s_barrier();                                                     \
    if ((t) + 2 < NT) {                                                               \
        STAGE(Ab + ((t) + 2) * 64, Bb + ((t) + 2) * 64, CA, CB)                       \
        asm volatile("s_waitcnt vmcnt(8)" ::: "memory");                              \
    } else if ((t) + 1 < NT) {                                                        \
        asm volatile("s_waitcnt vmcnt(0)" ::: "memory");                              \
    }                                                                                 \
    __builtin_amdgcn_sched_barrier(0);                                                \
    if ((t) + 1 < NT) { LB(bfrA, o0, NB) LA(afA, 0, o0, NA) }

    // prologue: stage tiles 0,1
    STAGE(Ab, Bb, A0, B0)
    STAGE(Ab + 64, Bb + 64, A1, B1)
    asm volatile("s_waitcnt vmcnt(8)" ::: "memory");
    __builtin_amdgcn_s_barrier();
    LB(bfrA, o0, B0) LA(afA, 0, o0, A0)

#pragma unroll 1
    for (int t = 0; t < NT; t += 2) {
        TILE(A0, B0, A1, B1, t)
        TILE(A1, B1, A0, B0, t + 1)
    }
#undef STAGE
#undef LA
#undef LB
#undef WAITL
#undef MM
#undef TILE
}

// EPI: 10 = UV merged (u | vT | bS by bx)   2 = gated(PV*u)   3 = out f32(+o_b+x)
template <int EPI, bool SWZ, int NT>
__global__ __launch_bounds__(512, 2) void kP(const unsigned short* __restrict__ A,
                                             const unsigned short* __restrict__ B,
                                             long long strideA, long long strideB,
                                             void* p0, void* p1, void* p2,
                                             const void* p3) {
    constexpr int K = NT * 64;
    __shared__ __align__(16) char As[2][256 * 128];
    __shared__ __align__(16) char Bs[2][256 * 128];
    int tid = threadIdx.x;
    int w = tid >> 6, lane = tid & 63;
    int wr = w >> 2, wc = w & 3;
    int c15 = lane & 15, qq = lane >> 4;
    int g = (c15 & 7) << 4;
    int o0 = c15 * 128 + ((qq * 16) ^ g);
    int o1 = c15 * 128 + ((64 + qq * 16) ^ g);
    int bx = blockIdx.x, by = blockIdx.y, bz = blockIdx.z;
    if constexpr (SWZ) {
        int gx = gridDim.x;
        int nb = gx * gridDim.y;
        int bid = by * gx + bx;
        int s = (bid & 7) * (nb >> 3) + (bid >> 3);
        bx = s % gx;
        by = s / gx;
    }
    const unsigned short* Ab = A + bz * strideA + (long long)by * 256 * K;
    const unsigned short* Bb = B + bz * strideB + (long long)bx * 256 * K;

    f32x4 acc[8][4];
#pragma unroll
    for (int m = 0; m < 8; ++m)
#pragma unroll
        for (int n = 0; n < 4; ++n) acc[m][n] = (f32x4){0.f, 0.f, 0.f, 0.f};

    bool swapped = true;
    if constexpr (EPI == 10) {
        swapped = !(bx >= 6 && bx < 12);
        if (swapped)
            kloopP<true, NT>(Ab, Bb, As[0], As[1], Bs[0], Bs[1], acc, tid, wr, wc, o0, o1);
        else
            kloopP<false, NT>(Ab, Bb, As[0], As[1], Bs[0], Bs[1], acc, tid, wr, wc, o0, o1);
    } else {
        kloopP<true, NT>(Ab, Bb, As[0], As[1], Bs[0], Bs[1], acc, tid, wr, wc, o0, o1);
    }

    if constexpr (EPI == 10) {
        if (swapped) {  // u (bx<6) or bS (bx==12): C^T frags -> row-major stores
            int rowb = by * 256 + wr * 128 + c15;
            int colb = bx * 256 + wc * 64 + (qq << 2);
#pragma unroll
            for (int m = 0; m < 8; ++m) {
#pragma unroll
                for (int n = 0; n < 4; ++n) {
                    int R = rowb + m * 16;
                    int C = colb + n * 16;
                    f32x4 a = acc[m][n];
                    if (C < 1536) {
                        f32x4 bb = *(const f32x4*)((const float*)p3 + C);
                        u16x4 o;
#pragma unroll
                        for (int i = 0; i < 4; ++i) o[i] = f2b(silu(a[i] + bb[i]));
                        *(u16x4*)((unsigned short*)p0 + (long long)R * 1536 + C) = o;
                    } else if (C < 3200) {  // bS
                        f32x4 bb = *(const f32x4*)((const float*)p3 + C);
                        u16x4 o;
#pragma unroll
                        for (int i = 0; i < 4; ++i) o[i] = f2b(silu(a[i] + bb[i]));
                        *(u16x4*)((unsigned short*)p2 + (long long)R * 128 + (C - 3072)) = o;
                    }
                }
            }
        } else {  // vT: thread holds 4 consecutive out-rows at one col
            int rowb = by * 256 + wr * 128 + (qq << 2);
            int colb = bx * 256 + wc * 64 + c15;
#pragma unroll
            for (int m = 0; m < 8; ++m) {
#pragma unroll
                for (int n = 0; n < 4; ++n) {
                    int R = rowb + m * 16;
                    int C = colb + n * 16;  // 1536..3071
                    float bias = ((const float*)p3)[C];
                    f32x4 a = acc[m][n];
                    u16x4 o;
#pragma unroll
                    for (int i = 0; i < 4; ++i) o[i] = f2b(silu(a[i] + bias));
                    int bb2 = R >> 9, mm = R & 511;
                    *(u16x4*)((unsigned short*)p1 +
                              ((long long)bb2 * 1536 + (C - 1536)) * 512 + mm) = o;
                }
            }
        }
    } else if constexpr (EPI == 2) {
        int rowb = by * 256 + wr * 128 + c15;
        int colb = bx * 256 + wc * 64 + (qq << 2);
#pragma unroll
        for (int m = 0; m < 8; ++m) {
#pragma unroll
            for (int n = 0; n < 4; ++n) {
                int R = rowb + m * 16;
                int C = colb + n * 16;
                f32x4 a = acc[m][n];
                long long idx = ((long long)(bz * 512 + R)) * 1536 + C;
                u16x4 uu = *(const u16x4*)((const unsigned short*)p1 + idx);
                u16x4 o;
#pragma unroll
                for (int i = 0; i < 4; ++i) o[i] = f2b(a[i] * b2f(uu[i]));
                *(u16x4*)((unsigned short*)p0 + idx) = o;
            }
        }
    } else {  // EPI == 3
        int rowb = by * 256 + wr * 128 + c15;
        int colb = bx * 256 + wc * 64 + (qq << 2);
#pragma unroll
        for (int m = 0; m < 8; ++m) {
#pragma unroll
            for (int n = 0; n < 4; ++n) {
                int R = rowb + m * 16;
                int C = colb + n * 16;
                f32x4 a = acc[m][n];
                long long idx = (long long)R * 768 + C;
                f32x4 xv = *(const f32x4*)((const float*)p2 + idx);
                f32x4 ob = *(const f32x4*)((const float*)p1 + C);
                f32x4 o;
#pragma unroll
                for (int i = 0; i < 4; ++i) o[i] = a[i] + ob[i] + xv[i];
                *(f32x4*)((float*)p0 + idx) = o;
            }
        }
    }
}

extern "C" void kernel_launch(void* const* d_in, const int* in_sizes, int n_in,
                              void* d_out, int out_size, void* d_ws, size_t ws_size,
                              hipStream_t stream) {
    const float* x     = (const float*)d_in[0];
    const float* ln_g  = (const float*)d_in[1];
    const float* ln_b  = (const float*)d_in[2];
    const float* uv_W  = (const float*)d_in[3];
    const float* uv_b  = (const float*)d_in[4];
    const float* g_qk  = (const float*)d_in[5];
    const float* b_qk  = (const float*)d_in[6];
    const float* w_rel = (const float*)d_in[7];
    const float* o_W   = (const float*)d_in[8];
    const float* o_b   = (const float*)d_in[9];
    float* out = (float*)d_out;

    char* ws = (char*)d_ws;
    size_t off = 0;
    auto alloc = [&](size_t bytes) {
        void* p = ws + off;
        off += (bytes + 255) & ~(size_t)255;
        return p;
    };
    unsigned short* uvWT = (unsigned short*)alloc(3328ll * 768 * 2);  // rows 3200+ = pad
    unsigned short* oWT  = (unsigned short*)alloc(768ll * 1536 * 2);
    unsigned short* xn   = (unsigned short*)alloc(16384ll * 768 * 2);
    unsigned short* u    = (unsigned short*)alloc(16384ll * 1536 * 2);
    unsigned short* vT   = (unsigned short*)alloc(32ll * 1536 * 512 * 2);
    unsigned short* bS   = (unsigned short*)alloc(16384ll * 128 * 2);
    unsigned short* q    = (unsigned short*)alloc(32ll * 512 * 128 * 2);
    unsigned short* k    = (unsigned short*)alloc(32ll * 512 * 128 * 2);
    unsigned short* P     = xn;  // alias: xn dead after UV kernel
    unsigned short* gated = u;   // alias: same-thread read-then-write

    k_convT<<<dim3(100, 24), dim3(32, 8), 0, stream>>>(uv_W, uvWT, 768, 3200);
    k_convT<<<dim3(24, 48), dim3(32, 8), 0, stream>>>(o_W, oWT, 1536, 768);
    k_ln<<<16384, 256, 0, stream>>>(x, ln_g, ln_b, xn);
    // UV merged: u | vT | bS   (N=3328 incl. 128 masked cols; K=768 -> NT=12)
    kP<10, true, 12><<<dim3(13, 64), 512, 0, stream>>>(
        xn, uvWT, 0, 0, (void*)u, (void*)vT, (void*)bS, (const void*)uv_b);
    k_rope<<<16384, 128, 0, stream>>>(bS, g_qk, b_qk, q, k);
    // QK^T -> P
    k_qk<<<dim3(4, 4, 32), 256, 0, stream>>>(q, k, w_rel, P);
    // PV gated by u   (K=512 -> NT=8)
    kP<2, false, 8><<<dim3(6, 2, 32), 512, 0, stream>>>(
        P, vT, 512ll * 512, 1536ll * 512, (void*)gated, (void*)u, nullptr, nullptr);
    // out = gated @ oWT^T + o_b + x   (K=1536 -> NT=24)
    kP<3, true, 24><<<dim3(3, 64), 512, 0, stream>>>(
        gated, oWT, 0, 0, (void*)out, (void*)o_b, (void*)x, nullptr);
}